// Round 5
// baseline (626.258 us; speedup 1.0000x reference)
//
#include <hip/hip_runtime.h>

#define FM_C   256
#define FM_H   200
#define FM_W   336
#define CROP   14
#define NSAMP  (CROP * CROP)     // 196
#define HW     (FM_H * FM_W)     // 67200
#define CPB    64                // channels per block  (grid.y = 4)
#define NC     4                 // channels staged per phase
#define NPH    (CPB / NC)        // 16 phases
#define PITCH  100               // floats per staged LDS row (>= max span ~99)
#define SEGS   (NC * 2 * CROP)   // 112 row-segments per phase
#define SPANQ  (PITCH / 4)       // 25 float4 slots per row
#define THREADS 256

__global__ __launch_bounds__(THREADS)
void roialign_kernel(const float* __restrict__ fm,
                     const float* __restrict__ boxes,
                     const int* __restrict__ box_ind,
                     float* __restrict__ out)
{
    // Staged featuremap rows: NC channels x 28 rows x PITCH floats = 44.8 KB
    __shared__ __align__(16) float L[NC * 2 * CROP * PITCH];
    // Per-i / per-j interpolation tables (in_y depends only on i, in_x only on j)
    __shared__ float s_yf[CROP], s_xf[CROP], s_my[CROP], s_mx[CROP];
    __shared__ int   s_x0i[CROP], s_x1i[CROP], s_yrow[2 * CROP];

    const int m  = blockIdx.x;        // box index
    const int cg = blockIdx.y;        // channel group
    const int t  = threadIdx.x;

    // ---- Phase 1: per-row/col interpolation params (bit-identical to prior kernel) ----
    if (t < CROP) {
        const float bx1 = boxes[4 * m + 0];
        const float by1 = boxes[4 * m + 1];
        const float bx2 = boxes[4 * m + 2];
        const float by2 = boxes[4 * m + 3];

        const float spacing_w = __fdiv_rn(__fsub_rn(bx2, bx1), 14.0f);
        const float spacing_h = __fdiv_rn(__fsub_rn(by2, by1), 14.0f);
        const float nx0 = __fdiv_rn(__fsub_rn(__fadd_rn(bx1, __fdiv_rn(spacing_w, 2.0f)), 0.5f), 335.0f);
        const float ny0 = __fdiv_rn(__fsub_rn(__fadd_rn(by1, __fdiv_rn(spacing_h, 2.0f)), 0.5f), 199.0f);
        const float nw  = __fdiv_rn(__fmul_rn(spacing_w, 13.0f), 335.0f);
        // Reference quirk: nh uses spacing_w. Must match.
        const float nh  = __fdiv_rn(__fmul_rn(spacing_w, 13.0f), 199.0f);

        const float y1n = ny0, x1n = nx0;
        const float y2n = __fadd_rn(ny0, nh);
        const float x2n = __fadd_rn(nx0, nw);

        const float step_y = __fdiv_rn(__fmul_rn(__fsub_rn(y2n, y1n), 199.0f), 13.0f);
        const float step_x = __fdiv_rn(__fmul_rn(__fsub_rn(x2n, x1n), 335.0f), 13.0f);
        const float in_y = __fadd_rn(__fmul_rn(y1n, 199.0f), __fmul_rn((float)t, step_y));
        const float in_x = __fadd_rn(__fmul_rn(x1n, 335.0f), __fmul_rn((float)t, step_x));

        const float y0f = floorf(in_y);
        const float x0f = floorf(in_x);
        const int y0i = (int)fminf(fmaxf(y0f, 0.0f), 199.0f);
        const int y1i = (int)fminf(fmaxf(__fadd_rn(y0f, 1.0f), 0.0f), 199.0f);
        const int x0i = (int)fminf(fmaxf(x0f, 0.0f), 335.0f);
        const int x1i = (int)fminf(fmaxf(__fadd_rn(x0f, 1.0f), 0.0f), 335.0f);

        s_yf[t] = __fsub_rn(in_y, y0f);
        s_xf[t] = __fsub_rn(in_x, x0f);
        s_my[t] = ((in_y >= 0.0f) && (in_y <= 199.0f)) ? 1.0f : 0.0f;
        s_mx[t] = ((in_x >= 0.0f) && (in_x <= 335.0f)) ? 1.0f : 0.0f;
        s_x0i[t] = x0i;
        s_x1i[t] = x1i;
        s_yrow[2 * t]     = y0i;
        s_yrow[2 * t + 1] = y1i;
    }
    __syncthreads();

    // in_x is strictly increasing in j -> x0i[0] is min, x1i[13] is max.
    const int xlo_al = s_x0i[0] & ~3;                       // 16B-aligned x base
    const int spanr  = (s_x1i[CROP - 1] - xlo_al + 4) & ~3; // rounded-up span <= PITCH

    const int b = box_ind[m];
    const float* __restrict__ fm_b  = fm  + ((size_t)b * FM_C + (size_t)cg * CPB) * HW;
    float*       __restrict__ out_b = out + ((size_t)m * FM_C + (size_t)cg * CPB) * NSAMP;

    for (int ph = 0; ph < NPH; ++ph) {
        const float* __restrict__ fm_ph = fm_b + (size_t)ph * NC * HW;

        // ---- Stage: 28 sampled rows x NC channels, contiguous float4 loads ----
        for (int idx = t; idx < SEGS * SPANQ; idx += THREADS) {
            const int seg = idx / SPANQ;          // compile-time divisor (25)
            const int q   = idx - seg * SPANQ;
            const int x4  = 4 * q;
            if (x4 < spanr) {
                const int c_l = seg / (2 * CROP); // compile-time divisor (28)
                const int r   = seg - c_l * (2 * CROP);
                const int y   = s_yrow[r];
                int xb = xlo_al + x4;
                if (xb > FM_W - 4) xb = FM_W - 4; // exact for all needed offsets (xb mult of 4)
                const float4 v = *(const float4*)(fm_ph + c_l * HW + y * FM_W + xb);
                *(float4*)&L[seg * PITCH + x4] = v;
            }
        }
        __syncthreads();

        // ---- Compute: NC*196 outputs from LDS ----
        for (int w = t; w < NC * NSAMP; w += THREADS) {
            const int c_l = w / NSAMP;            // compile-time divisor (196)
            const int s   = w - c_l * NSAMP;
            const int i   = s / CROP;             // compile-time divisor (14)
            const int j   = s - i * CROP;

            const float yf = s_yf[i];
            const float xf = s_xf[j];
            const float mk = __fmul_rn(s_my[i], s_mx[j]);
            const int off0 = s_x0i[j] - xlo_al;
            const int off1 = s_x1i[j] - xlo_al;

            const float* Lr = &L[c_l * (2 * CROP * PITCH) + (2 * i) * PITCH];
            const float tl = Lr[off0];
            const float tr = Lr[off1];
            const float bl = Lr[PITCH + off0];
            const float br = Lr[PITCH + off1];

            const float top = __fadd_rn(tl, __fmul_rn(__fsub_rn(tr, tl), xf));
            const float bot = __fadd_rn(bl, __fmul_rn(__fsub_rn(br, bl), xf));
            const float o   = __fadd_rn(top, __fmul_rn(__fsub_rn(bot, top), yf));
            out_b[ph * (NC * NSAMP) + w] = __fmul_rn(o, mk);
        }
        __syncthreads();
    }
}

extern "C" void kernel_launch(void* const* d_in, const int* in_sizes, int n_in,
                              void* d_out, int out_size, void* d_ws, size_t ws_size,
                              hipStream_t stream) {
    const float* fm      = (const float*)d_in[0];
    const float* boxes   = (const float*)d_in[1];
    const int*   box_ind = (const int*)d_in[2];
    float*       out     = (float*)d_out;

    const int M = in_sizes[2];            // number of boxes (1024)

    dim3 grid(M, FM_C / CPB);             // (1024, 4)
    roialign_kernel<<<grid, THREADS, 0, stream>>>(fm, boxes, box_ind, out);
}

// Round 6
// 305.010 us; speedup vs baseline: 2.0532x; 2.0532x over previous
//
#include <hip/hip_runtime.h>

#define FM_C   256
#define FM_H   200
#define FM_W   336
#define CROP   14
#define NSAMP  (CROP * CROP)     // 196
#define HW     (FM_H * FM_W)     // 67200
#define CPB    32                // channels per block -> grid.y = 8
#define THREADS 256

__global__ __launch_bounds__(THREADS)
void roialign_kernel(const float* __restrict__ fm,
                     const float* __restrict__ boxes,
                     const int* __restrict__ box_ind,
                     float* __restrict__ out)
{
    const int m  = blockIdx.x;        // box index (fastest -> L3 slice locality)
    const int cg = blockIdx.y;        // channel group
    const int t  = threadIdx.x;
    // Row-aligned lane mapping: each wave = 4 crop rows x 14 consecutive-x samples.
    const int i  = t >> 4;            // 0..15 (crop row; 14,15 idle)
    const int j  = t & 15;            // 0..15 (crop col; 14,15 idle)
    if (i >= CROP || j >= CROP) return;

    // ---- per-thread interpolation params (bit-identical op order to verified R3) ----
    const float bx1 = boxes[4 * m + 0];
    const float by1 = boxes[4 * m + 1];
    const float bx2 = boxes[4 * m + 2];
    const float by2 = boxes[4 * m + 3];

    const float spacing_w = __fdiv_rn(__fsub_rn(bx2, bx1), 14.0f);
    const float spacing_h = __fdiv_rn(__fsub_rn(by2, by1), 14.0f);
    const float nx0 = __fdiv_rn(__fsub_rn(__fadd_rn(bx1, __fdiv_rn(spacing_w, 2.0f)), 0.5f), 335.0f);
    const float ny0 = __fdiv_rn(__fsub_rn(__fadd_rn(by1, __fdiv_rn(spacing_h, 2.0f)), 0.5f), 199.0f);
    const float nw  = __fdiv_rn(__fmul_rn(spacing_w, 13.0f), 335.0f);
    // Reference quirk: nh uses spacing_w. Must match.
    const float nh  = __fdiv_rn(__fmul_rn(spacing_w, 13.0f), 199.0f);

    const float y1n = ny0, x1n = nx0;
    const float y2n = __fadd_rn(ny0, nh);
    const float x2n = __fadd_rn(nx0, nw);

    const float step_y = __fdiv_rn(__fmul_rn(__fsub_rn(y2n, y1n), 199.0f), 13.0f);
    const float step_x = __fdiv_rn(__fmul_rn(__fsub_rn(x2n, x1n), 335.0f), 13.0f);
    const float in_y = __fadd_rn(__fmul_rn(y1n, 199.0f), __fmul_rn((float)i, step_y));
    const float in_x = __fadd_rn(__fmul_rn(x1n, 335.0f), __fmul_rn((float)j, step_x));

    const bool valid = (in_y >= 0.0f) && (in_y <= 199.0f) &&
                       (in_x >= 0.0f) && (in_x <= 335.0f);
    const float mk = valid ? 1.0f : 0.0f;

    const float y0f = floorf(in_y);
    const float x0f = floorf(in_x);
    const float yf  = __fsub_rn(in_y, y0f);
    const float xf  = __fsub_rn(in_x, x0f);
    const int y0i = (int)fminf(fmaxf(y0f, 0.0f), 199.0f);
    const int y1i = (int)fminf(fmaxf(__fadd_rn(y0f, 1.0f), 0.0f), 199.0f);
    const int x0i = (int)fminf(fmaxf(x0f, 0.0f), 335.0f);
    const int x1i = (int)fminf(fmaxf(__fadd_rn(x0f, 1.0f), 0.0f), 335.0f);

    const int b = box_ind[m];
    const float* __restrict__ p = fm + ((size_t)b * FM_C + (size_t)cg * CPB) * HW;
    const int o_tl = y0i * FM_W + x0i;
    const int o_tr = y0i * FM_W + x1i;
    const int o_bl = y1i * FM_W + x0i;
    const int o_br = y1i * FM_W + x1i;

    float* __restrict__ op = out + ((size_t)m * FM_C + (size_t)cg * CPB) * NSAMP
                                 + i * CROP + j;

    #pragma unroll 4
    for (int c = 0; c < CPB; ++c) {
        const float tl = p[o_tl];
        const float tr = p[o_tr];
        const float bl = p[o_bl];
        const float br = p[o_br];
        p += HW;
        const float top = __fadd_rn(tl, __fmul_rn(__fsub_rn(tr, tl), xf));
        const float bot = __fadd_rn(bl, __fmul_rn(__fsub_rn(br, bl), xf));
        const float o   = __fadd_rn(top, __fmul_rn(__fsub_rn(bot, top), yf));
        *op = __fmul_rn(o, mk);
        op += NSAMP;
    }
}

extern "C" void kernel_launch(void* const* d_in, const int* in_sizes, int n_in,
                              void* d_out, int out_size, void* d_ws, size_t ws_size,
                              hipStream_t stream) {
    const float* fm      = (const float*)d_in[0];
    const float* boxes   = (const float*)d_in[1];
    const int*   box_ind = (const int*)d_in[2];
    float*       out     = (float*)d_out;

    const int M = in_sizes[2];            // number of boxes (1024)

    dim3 grid(M, FM_C / CPB);             // (1024, 8)
    roialign_kernel<<<grid, THREADS, 0, stream>>>(fm, boxes, box_ind, out);
}

// Round 8
// 180.413 us; speedup vs baseline: 3.4712x; 1.6906x over previous
//
#include <hip/hip_runtime.h>

#define FM_N   4
#define FM_C   256
#define FM_H   200
#define FM_W   336
#define CROP   14
#define NSAMP  (CROP * CROP)     // 196
#define HW     (FM_H * FM_W)     // 67200
#define CPB    8                 // channels per (box, slice) block
#define NCG    (FM_C / CPB)      // 32 slices
#define NCGH   (NCG / 2)         // 16 slices per XCD-owned half
#define THREADS 256

// 8-byte pair load with natural 4-byte alignment (safe for any float index)
typedef struct { float x, y; } f2s;

// ---------------- Kernel 1: bucket boxes by image (stable counting sort) -------------
__global__ __launch_bounds__(THREADS)
void bucket_kernel(const int* __restrict__ box_ind, int M,
                   int* __restrict__ perm, int* __restrict__ base)
{
    __shared__ int cnt[FM_N][THREADS];
    __shared__ int tot[FM_N], sbase[FM_N + 1];
    const int t = threadIdx.x;
    const int E = (M + THREADS - 1) / THREADS;

    int local[FM_N] = {0, 0, 0, 0};
    for (int e = 0; e < E; ++e) {
        const int idx = t * E + e;
        if (idx < M) local[box_ind[idx] & 3]++;
    }
    for (int b = 0; b < FM_N; ++b) cnt[b][t] = local[b];
    __syncthreads();
    if (t < FM_N) {                       // serial exclusive scan per bucket
        int run = 0;
        for (int k = 0; k < THREADS; ++k) { const int c = cnt[t][k]; cnt[t][k] = run; run += c; }
        tot[t] = run;
    }
    __syncthreads();
    if (t == 0) {
        sbase[0] = 0;
        for (int b = 0; b < FM_N; ++b) sbase[b + 1] = sbase[b] + tot[b];
        for (int b = 0; b <= FM_N; ++b) base[b] = sbase[b];
    }
    __syncthreads();
    int off[FM_N];
    for (int b = 0; b < FM_N; ++b) off[b] = sbase[b] + cnt[b][t];
    for (int e = 0; e < E; ++e) {
        const int idx = t * E + e;
        if (idx < M) { const int v = box_ind[idx] & 3; perm[off[v]++] = idx; }
    }
}

// ---------------- Kernel 2: RoIAlign, XCD-owned (image, channel-half) ----------------
__global__ __launch_bounds__(THREADS)
void roialign_kernel(const float* __restrict__ fm,
                     const float* __restrict__ boxes,
                     const int* __restrict__ perm,
                     const int* __restrict__ base,
                     float* __restrict__ out)
{
    const int xcd = blockIdx.x & 7;       // hardware round-robin: linear_id % 8 -> XCD
    const int l   = blockIdx.x >> 3;
    const int I   = xcd >> 1;             // owned image (0..3)
    const int h   = xcd & 1;              // owned channel half (0..1)
    const int b0  = base[I];
    const int nI  = base[I + 1] - b0;     // boxes in this image
    const int perXcdX = gridDim.x >> 3;
    const int slots   = perXcdX * gridDim.y;
    const int w0      = blockIdx.y * perXcdX + l;

    const int t = threadIdx.x;
    const int i = t >> 4;                 // crop row (14,15 idle)
    const int j = t & 15;                 // crop col (14,15 idle)
    const bool act = (i < CROP) && (j < CROP);

    const int work = nI * NCGH;           // (box, slice-in-half) items
    for (int w = w0; w < work; w += slots) {
        const int cgh = w / nI;           // slice-major: whole slice resident per XCD
        const int mi  = w - cgh * nI;
        const int m   = perm[b0 + mi];    // original box id; its image == I
        const int cg  = h * NCGH + cgh;

        if (act) {
            // ---- per-thread interpolation params (bit-identical op order) ----
            const float bx1 = boxes[4 * m + 0];
            const float by1 = boxes[4 * m + 1];
            const float bx2 = boxes[4 * m + 2];
            const float by2 = boxes[4 * m + 3];

            const float spacing_w = __fdiv_rn(__fsub_rn(bx2, bx1), 14.0f);
            const float spacing_h = __fdiv_rn(__fsub_rn(by2, by1), 14.0f);
            const float nx0 = __fdiv_rn(__fsub_rn(__fadd_rn(bx1, __fdiv_rn(spacing_w, 2.0f)), 0.5f), 335.0f);
            const float ny0 = __fdiv_rn(__fsub_rn(__fadd_rn(by1, __fdiv_rn(spacing_h, 2.0f)), 0.5f), 199.0f);
            const float nw  = __fdiv_rn(__fmul_rn(spacing_w, 13.0f), 335.0f);
            // Reference quirk: nh uses spacing_w. Must match.
            const float nh  = __fdiv_rn(__fmul_rn(spacing_w, 13.0f), 199.0f);

            const float y1n = ny0, x1n = nx0;
            const float y2n = __fadd_rn(ny0, nh);
            const float x2n = __fadd_rn(nx0, nw);

            const float step_y = __fdiv_rn(__fmul_rn(__fsub_rn(y2n, y1n), 199.0f), 13.0f);
            const float step_x = __fdiv_rn(__fmul_rn(__fsub_rn(x2n, x1n), 335.0f), 13.0f);
            const float in_y = __fadd_rn(__fmul_rn(y1n, 199.0f), __fmul_rn((float)i, step_y));
            const float in_x = __fadd_rn(__fmul_rn(x1n, 335.0f), __fmul_rn((float)j, step_x));

            const bool valid = (in_y >= 0.0f) && (in_y <= 199.0f) &&
                               (in_x >= 0.0f) && (in_x <= 335.0f);
            const float mk = valid ? 1.0f : 0.0f;

            const float y0f = floorf(in_y);
            const float x0f = floorf(in_x);
            const float yf  = __fsub_rn(in_y, y0f);
            const float xf  = __fsub_rn(in_x, x0f);
            const int y0i = (int)fminf(fmaxf(y0f, 0.0f), 199.0f);
            const int y1i = (int)fminf(fmaxf(__fadd_rn(y0f, 1.0f), 0.0f), 199.0f);
            const int x0i = (int)fminf(fmaxf(x0f, 0.0f), 335.0f);
            const int x1i = (int)fminf(fmaxf(__fadd_rn(x0f, 1.0f), 0.0f), 335.0f);

            // Merged-pair gather: x0i,x1i both lie in {xa, xa+1}
            const int  xa   = min(x0i, FM_W - 2);
            const bool sel0 = (x0i != xa);
            const bool sel1 = (x1i != xa);
            const int  oya  = y0i * FM_W + xa;
            const int  oyb  = y1i * FM_W + xa;

            const float* __restrict__ pc =
                fm + ((size_t)I * FM_C + (size_t)cg * CPB) * HW;
            float* __restrict__ op =
                out + ((size_t)m * FM_C + (size_t)cg * CPB) * NSAMP + i * CROP + j;

            #pragma unroll
            for (int c = 0; c < CPB; ++c) {
                const f2s va = *(const f2s*)(pc + oya);   // (f[xa], f[xa+1]) top row
                const f2s vb = *(const f2s*)(pc + oyb);   // bottom row
                pc += HW;
                const float tl = sel0 ? va.y : va.x;
                const float tr = sel1 ? va.y : va.x;
                const float bl = sel0 ? vb.y : vb.x;
                const float br = sel1 ? vb.y : vb.x;
                const float top = __fadd_rn(tl, __fmul_rn(__fsub_rn(tr, tl), xf));
                const float bot = __fadd_rn(bl, __fmul_rn(__fsub_rn(br, bl), xf));
                const float o   = __fadd_rn(top, __fmul_rn(__fsub_rn(bot, top), yf));
                *op = __fmul_rn(o, mk);
                op += NSAMP;
            }
        }
    }
}

extern "C" void kernel_launch(void* const* d_in, const int* in_sizes, int n_in,
                              void* d_out, int out_size, void* d_ws, size_t ws_size,
                              hipStream_t stream) {
    const float* fm      = (const float*)d_in[0];
    const float* boxes   = (const float*)d_in[1];
    const int*   box_ind = (const int*)d_in[2];
    float*       out     = (float*)d_out;

    const int M = in_sizes[2];            // number of boxes (1024)

    int* perm = (int*)d_ws;               // [M]
    int* base = perm + M;                 // [5]

    bucket_kernel<<<1, THREADS, 0, stream>>>(box_ind, M, perm, base);

    const int gx = ((2 * M + 7) / 8) * 8; // 2048: 2x slot slack per XCD, %8 == 0
    dim3 grid(gx, NCG);
    roialign_kernel<<<grid, THREADS, 0, stream>>>(fm, boxes, perm, base, out);
}